// Round 4
// baseline (406.359 us; speedup 1.0000x reference)
//
#include <hip/hip_runtime.h>

#define C 10
#define CHUNK_ROWS 128          // rows per wave-chunk
#define CHUNK_FLOATS 1280       // 128 * 10

__device__ __forceinline__ float waveSum(float v) {
#pragma unroll
  for (int o = 32; o > 0; o >>= 1) v += __shfl_down(v, o, 64);
  return v;
}
__device__ __forceinline__ float waveMin(float v) {
#pragma unroll
  for (int o = 32; o > 0; o >>= 1) v = fminf(v, __shfl_down(v, o, 64));
  return v;
}
__device__ __forceinline__ float waveMax(float v) {
#pragma unroll
  for (int o = 32; o > 0; o >>= 1) v = fmaxf(v, __shfl_down(v, o, 64));
  return v;
}
__device__ __forceinline__ unsigned waveMaxU(unsigned v) {
#pragma unroll
  for (int o = 32; o > 0; o >>= 1) {
    unsigned w = (unsigned)__shfl_down((int)v, o, 64);
    v = v > w ? v : w;
  }
  return v;
}

// async global->LDS, 16B per lane; lane-contiguous addresses (m97 pattern)
#define GLD16(gp, lp)                                             \
  __builtin_amdgcn_global_load_lds(                               \
      (__attribute__((address_space(1))) void*)(gp),              \
      (__attribute__((address_space(3))) void*)(lp), 16, 0, 0)

// ---------------- pass 1: wave-autonomous double-buffered streaming.
// Each wave owns a private LDS slice (2 bufs x (probs 5120B + y 5120B)) and
// processes 128-row chunks with NO __syncthreads in the loop -> compiler emits
// fine-grained vmcnt waits; chunk t+1's 10 loads stay in flight over chunk t's
// compute. 2-wave blocks, 40KB LDS -> 4 blocks/CU, all 1024 blocks co-resident.
__global__ __launch_bounds__(128, 2) void pass1(
    const float* __restrict__ probs, const float* __restrict__ y,
    float2* __restrict__ us2,
    unsigned* __restrict__ uminInvSlots, unsigned* __restrict__ umaxSlots,
    float* __restrict__ ceSlots, float* __restrict__ focalSlots,
    int nchunks) {
  __shared__ float lds[2 * 2 * 2 * CHUNK_FLOATS];  // [wave][buf][p|y][1280] = 40960 B
  __shared__ float red[8];
  const int tid = threadIdx.x;
  const int widx = tid >> 6, lane = tid & 63;
  float* const wbase = lds + widx * (4 * CHUNK_FLOATS);

  const int gw = blockIdx.x * 2 + widx;   // global wave id, 0..2047
  const int NW = gridDim.x * 2;           // total waves

  // label0 = argmax of flattened y == label of sample 0 (first max). Cache-hit.
  int label0 = 0;
  {
    float m = y[0];
#pragma unroll
    for (int c = 1; c < C; ++c) {
      float v = y[c];
      if (v > m) { m = v; label0 = c; }
    }
  }

  auto issue = [&](int c, int b) {
    const size_t g = (size_t)c * CHUNK_FLOATS + (size_t)lane * 4;
    float* lp = wbase + b * (2 * CHUNK_FLOATS);
#pragma unroll
    for (int q = 0; q < 5; ++q)
      GLD16(probs + g + q * 256, lp + q * 256 + lane * 4);
#pragma unroll
    for (int q = 0; q < 5; ++q)
      GLD16(y + g + q * 256, lp + CHUNK_FLOATS + q * 256 + lane * 4);
  };

  float ceA = 0.f, foA = 0.f;
  float mnA = __uint_as_float(0x7f800000u), mxA = 0.f;

  if (gw < nchunks) issue(gw, 0);
  int b = 0;
  for (int c = gw; c < nchunks; c += NW, b ^= 1) {
    if (c + NW < nchunks) issue(c + NW, b ^ 1);

    // lane handles rows 2*lane, 2*lane+1 (80B, float4-aligned)
    const float4* pp = (const float4*)(wbase + b * (2 * CHUNK_FLOATS));
    const float4* yy = (const float4*)(wbase + b * (2 * CHUNK_FLOATS) + CHUNK_FLOATS);
    float P[20], Yv[20];
#pragma unroll
    for (int q = 0; q < 5; ++q) {
      float4 v = pp[lane * 5 + q];
      P[4 * q] = v.x; P[4 * q + 1] = v.y; P[4 * q + 2] = v.z; P[4 * q + 3] = v.w;
    }
#pragma unroll
    for (int q = 0; q < 5; ++q) {
      float4 v = yy[lane * 5 + q];
      Yv[4 * q] = v.x; Yv[4 * q + 1] = v.y; Yv[4 * q + 2] = v.z; Yv[4 * q + 3] = v.w;
    }

    int am0 = 0, am1 = 0;
    float m0 = P[0], m1 = P[10];
#pragma unroll
    for (int cc = 1; cc < C; ++cc) {  // strict > keeps first max (jnp.argmax)
      if (P[cc] > m0) { m0 = P[cc]; am0 = cc; }
      if (P[10 + cc] > m1) { m1 = P[10 + cc]; am1 = cc; }
    }
    float u0 = 0.f, u1 = 0.f, pl0 = 0.f, pl1 = 0.f;
#pragma unroll
    for (int cc = 0; cc < C; ++cc) {
      u0 -= P[cc] * __logf(fmaxf(P[cc], 1e-10f));
      u1 -= P[10 + cc] * __logf(fmaxf(P[10 + cc], 1e-10f));
      pl0 = fmaf(Yv[cc], P[cc], pl0);          // y one-hot: p at true label
      pl1 = fmaf(Yv[10 + cc], P[10 + cc], pl1);
    }
    float ce0 = -__logf(fmaxf(pl0, 1e-8f)), ce1 = -__logf(fmaxf(pl1, 1e-8f));
    ceA += ce0 + ce1;
    foA += ce0 * (1.f - pl0) + ce1 * (1.f - pl1);
    mnA = fminf(mnA, fminf(u0, u1));
    mxA = fmaxf(mxA, fmaxf(u0, u1));

    // pack acc into sign bit (unc >= 0; sign set == inaccurate), coalesced store
    unsigned s0 = __float_as_uint(u0) | ((am0 == label0) ? 0u : 0x80000000u);
    unsigned s1 = __float_as_uint(u1) | ((am1 == label0) ? 0u : 0x80000000u);
    us2[(size_t)c * 64 + lane] = make_float2(__uint_as_float(s0), __uint_as_float(s1));
  }

  // block reduce (2 waves), then spread-slot atomics (16 blocks per address)
  float ce = waveSum(ceA), fo = waveSum(foA);
  float mn = waveMin(mnA), mx = waveMax(mxA);
  if (lane == 0) { red[widx] = ce; red[2 + widx] = fo; red[4 + widx] = mn; red[6 + widx] = mx; }
  __syncthreads();
  if (tid == 0) {
    float tce = red[0] + red[1];
    float tfo = red[2] + red[3];
    float tmn = fminf(red[4], red[5]);
    float tmx = fmaxf(red[6], red[7]);
    int slot = blockIdx.x & 63;
    atomicAdd(&ceSlots[slot], tce);
    atomicAdd(&focalSlots[slot], tfo);
    atomicMax(&uminInvSlots[slot], ~__float_as_uint(tmn));  // min via inverted bits
    atomicMax(&umaxSlots[slot], __float_as_uint(tmx));
  }
}

// ---------------- pass 2: 22-bin x 4-category histogram; per-lane LDS columns,
// 4 waves share columns via ds_add_f32 (lane-indexed -> conflict/contention free).
// Block partials go to 64 spread slot-copies via global atomics (16 adds/address).
__global__ __launch_bounds__(256, 4) void pass2(
    const float4* __restrict__ us4, int n4,
    const unsigned* __restrict__ uminInvSlots, const unsigned* __restrict__ umaxSlots,
    float* __restrict__ ghist) {
  __shared__ float hist[88 * 64];  // [row][lane], 22528 B
  __shared__ float smm[2];
  const int tid = threadIdx.x, lane = tid & 63;
  for (int i = tid; i < 88 * 64; i += 256) hist[i] = 0.f;
  if (tid < 64) {
    unsigned mnInv = waveMaxU(uminInvSlots[tid]);
    unsigned mxb = waveMaxU(umaxSlots[tid]);
    if (tid == 0) { smm[0] = __uint_as_float(~mnInv); smm[1] = __uint_as_float(mxb); }
  }
  __syncthreads();
  const float umin = smm[0], delta = smm[1] - smm[0];
  float th[21];
#pragma unroll
  for (int k = 0; k < 21; ++k) th[k] = fmaf(0.05f * (float)k, delta, umin);

  const int stride = gridDim.x * 256;
  for (int i = blockIdx.x * 256 + tid; i < n4; i += stride) {
    float4 v = us4[i];
    float vv[4] = {v.x, v.y, v.z, v.w};
#pragma unroll
    for (int q = 0; q < 4; ++q) {
      unsigned b = __float_as_uint(vv[q]);
      int rb = (b >> 31) ? 44 : 0;  // acc rows 0..43, inacc rows 44..87
      float u = __uint_as_float(b & 0x7fffffffu);
      // soft_T: log(num/den) = log(num)-log(den); clamp matches frac clamp
      float e = u * 0.4342944819f;  // u / ln(10)
      float lnum = __logf(e * 0.9f);
      float lden = __logf(fmaxf((1.f - e) * 0.1f, 1e-10f));
      float x = fmaxf(lnum - lden, -23.0258509f) * 100.f;
      float s = __builtin_amdgcn_rcpf(1.f + __expf(-x));                   // sigmoid
      float t = 1.f - 2.f * __builtin_amdgcn_rcpf(__expf(2.f * u) + 1.f);  // tanh
      float wc = (1.f - s) * (1.f - t), wu = s * t;
      int j = 0;  // j = #{k: u > th_k}; le[k] <=> k >= j
#pragma unroll
      for (int k = 0; k < 21; ++k) j += (u > th[k]) ? 1 : 0;
      atomicAdd(&hist[(rb + j) * 64 + lane], wc);        // ds_add_f32
      atomicAdd(&hist[(rb + 22 + j) * 64 + lane], wu);
    }
  }
  __syncthreads();
  // tree-reduce 64 columns per row
#pragma unroll
  for (int st = 32; st >= 1; st >>= 1) {
    for (int idx = tid; idx < 88 * st; idx += 256) {
      int r = idx / st, c = idx - r * st;
      hist[r * 64 + c] += hist[r * 64 + c + st];
    }
    __syncthreads();
  }
  int slot = blockIdx.x & 63;
  for (int r = tid; r < 88; r += 256)
    atomicAdd(&ghist[slot * 88 + r], hist[r * 64]);
}

// ---------------- pass 3: reduce 64 slot-copies + scalar slots, emit outputs
__global__ __launch_bounds__(256) void pass3(
    const float* __restrict__ ghist,
    const float* __restrict__ ceSlots, const float* __restrict__ focalSlots,
    float* __restrict__ out, float invN) {
  __shared__ float hr[88];
  __shared__ float scf[2];
  int tid = threadIdx.x;
  if (tid < 88) {
    float s = 0.f;
    for (int q = 0; q < 64; ++q) s += ghist[q * 88 + tid];  // coalesced across tid
    hr[tid] = s;
  }
  if (tid >= 128 && tid < 192) {
    int l = tid - 128;
    float ce = waveSum(ceSlots[l]);
    float fo = waveSum(focalSlots[l]);
    if (l == 0) { scf[0] = ce; scf[1] = fo; }
  }
  __syncthreads();
  if (tid == 0) {
    float H0[22], H1[22], H2[22], H3[22];
    float totAU = 0.f, totIU = 0.f;
    for (int j = 0; j < 22; ++j) {
      H0[j] = hr[j]; H1[j] = hr[22 + j]; H2[j] = hr[44 + j]; H3[j] = hr[66 + j];
      totAU += H1[j]; totIU += H3[j];
    }
    float n_ac = 0.f, n_ic = 0.f, n_au = totAU, n_iu = totIU;
    float auc = 0.f, prev = 0.f;
    for (int k = 0; k < 21; ++k) {
      n_ac += H0[k]; n_ic += H2[k];
      n_au -= H1[k]; n_iu -= H3[k];
      float avu = (n_ac + n_iu) / (n_ac + n_au + n_ic + n_iu + 1e-10f);
      if (k > 0) auc += (avu + prev) * 0.5f * 0.05f;
      prev = avu;
    }
    out[0] = -logf(fmaxf(auc, 1e-10f)) + scf[1] * invN;
    out[1] = scf[0] * invN;
  }
}

extern "C" void kernel_launch(void* const* d_in, const int* in_sizes, int n_in,
                              void* d_out, int out_size, void* d_ws, size_t ws_size,
                              hipStream_t stream) {
  const float* probs = (const float*)d_in[0];
  const float* y = (const float*)d_in[1];
  float* out = (float*)d_out;
  const int N = in_sizes[0] / C;

  // ws layout (floats): [0,64) uminInv slots, [64,128) umax slots,
  // [128,192) ce slots, [192,256) focal slots, [256,5888) ghist[64][88],
  // [5888, 5888+N) us  (5888*4 = 23552 B, 16B-aligned)
  float* wsf = (float*)d_ws;
  unsigned* uminInvSlots = (unsigned*)wsf;
  unsigned* umaxSlots = (unsigned*)(wsf + 64);
  float* ceSlots = wsf + 128;
  float* focalSlots = wsf + 192;
  float* ghist = wsf + 256;
  float* us = wsf + 5888;

  hipMemsetAsync(d_ws, 0, 5888 * sizeof(float), stream);  // all accumulators -> 0

  const int nchunks = N / CHUNK_ROWS;  // N = 4194304 -> 32768
  pass1<<<1024, 128, 0, stream>>>(probs, y, (float2*)us, uminInvSlots, umaxSlots,
                                  ceSlots, focalSlots, nchunks);
  pass2<<<1024, 256, 0, stream>>>((const float4*)us, N / 4, uminInvSlots, umaxSlots,
                                  ghist);
  pass3<<<1, 256, 0, stream>>>(ghist, ceSlots, focalSlots, out, 1.0f / (float)N);
}

// Round 5
// 399.874 us; speedup vs baseline: 1.0162x; 1.0162x over previous
//
#include <hip/hip_runtime.h>

#define C 10
#define CHUNK_ROWS 128
#define CHUNK_FLOATS 1280   // 128 rows * 10

__device__ __forceinline__ float waveSum(float v) {
#pragma unroll
  for (int o = 32; o > 0; o >>= 1) v += __shfl_down(v, o, 64);
  return v;
}
__device__ __forceinline__ float waveMin(float v) {
#pragma unroll
  for (int o = 32; o > 0; o >>= 1) v = fminf(v, __shfl_down(v, o, 64));
  return v;
}
__device__ __forceinline__ float waveMax(float v) {
#pragma unroll
  for (int o = 32; o > 0; o >>= 1) v = fmaxf(v, __shfl_down(v, o, 64));
  return v;
}
__device__ __forceinline__ unsigned waveMaxU(unsigned v) {
#pragma unroll
  for (int o = 32; o > 0; o >>= 1) {
    unsigned w = (unsigned)__shfl_down((int)v, o, 64);
    v = v > w ? v : w;
  }
  return v;
}

// async global->LDS, 16B per lane; lane-contiguous addresses (m97 pattern)
#define GLD16(gp, lp)                                             \
  __builtin_amdgcn_global_load_lds(                               \
      (__attribute__((address_space(1))) void*)(gp),              \
      (__attribute__((address_space(3))) void*)(lp), 16, 0, 0)

// ---------------- pass 1: wave-autonomous streaming, no barriers in the loop.
// probs: GLD16 -> per-wave 2x5KB double buffer (row part: entropy/argmax; plus
// coalesced LDS re-read for elementwise lp8). y: coalesced float4 -> registers,
// prefetched one chunk ahead (ce/focal are pure elementwise sums - no rows).
// LDS/block = 4 waves * 10240 B = 40960 B exactly -> 4 blocks/CU, 16 waves/CU,
// grid 1024 = all co-resident, one generation, 8 chunks/wave.
__global__ __launch_bounds__(256, 4) void pass1(
    const float* __restrict__ probs, const float* __restrict__ y,
    float2* __restrict__ us2,
    unsigned* __restrict__ uminInvSlots, unsigned* __restrict__ umaxSlots,
    float* __restrict__ ceSlots, float* __restrict__ focalSlots,
    int nchunks) {
  __shared__ float lds[4 * 2 * CHUNK_FLOATS];  // [wave][buf][1280] = 40960 B
  const int tid = threadIdx.x;
  const int widx = tid >> 6, lane = tid & 63;
  float* const wbuf = lds + widx * (2 * CHUNK_FLOATS);

  const int gw = blockIdx.x * 4 + widx;  // global wave id
  const int NW = gridDim.x * 4;

  // label0 = argmax of flattened y == label of sample 0 (first max). Cache-hit.
  int label0 = 0;
  {
    float m = y[0];
#pragma unroll
    for (int c = 1; c < C; ++c) {
      float v = y[c];
      if (v > m) { m = v; label0 = c; }
    }
  }

  const float4* y4 = (const float4*)y;

  auto issueP = [&](int c, int b) {
    const float* gp = probs + (size_t)c * CHUNK_FLOATS + (size_t)lane * 4;
    float* lp = wbuf + b * CHUNK_FLOATS + lane * 4;
#pragma unroll
    for (int q = 0; q < 5; ++q) GLD16(gp + q * 256, lp + q * 256);
  };
  auto issueY = [&](int c, float4* Yr) {
    const float4* gy = y4 + (size_t)c * 320 + lane;
#pragma unroll
    for (int q = 0; q < 5; ++q) Yr[q] = gy[q * 64];
  };

  float ceA = 0.f, foA = 0.f;
  float mnA = __uint_as_float(0x7f800000u), mxA = 0.f;
  float4 Ycur[5], Ynxt[5];

  if (gw < nchunks) { issueP(gw, 0); issueY(gw, Ycur); }
  int b = 0;
  for (int c = gw; c < nchunks; c += NW, b ^= 1) {
    if (c + NW < nchunks) { issueP(c + NW, b ^ 1); issueY(c + NW, Ynxt); }
    const float4* buff4 = (const float4*)(wbuf + b * CHUNK_FLOATS);

    // ---- elementwise part: ce/focal from y (regs) x lp8(p) (coalesced LDS).
    // ce = -sum y*log(max(p,1e-8)); focal = -sum y*log(max(p,1e-8))*(1-p).
#pragma unroll
    for (int q = 0; q < 5; ++q) {
      float4 pv = buff4[q * 64 + lane];  // same 16B this lane GLD16'd
      float4 yv = Ycur[q];
      float lpx = __logf(fmaxf(pv.x, 1e-8f));
      float lpy = __logf(fmaxf(pv.y, 1e-8f));
      float lpz = __logf(fmaxf(pv.z, 1e-8f));
      float lpw = __logf(fmaxf(pv.w, 1e-8f));
      float tx = yv.x * lpx, ty = yv.y * lpy, tz = yv.z * lpz, tw = yv.w * lpw;
      ceA -= tx + ty + tz + tw;
      foA -= tx * (1.f - pv.x) + ty * (1.f - pv.y) + tz * (1.f - pv.z) + tw * (1.f - pv.w);
    }

    // ---- row part: lane owns rows 2*lane, 2*lane+1 (80 B = 5 float4)
    float P[20];
#pragma unroll
    for (int q = 0; q < 5; ++q) {
      float4 v = buff4[lane * 5 + q];
      P[4 * q] = v.x; P[4 * q + 1] = v.y; P[4 * q + 2] = v.z; P[4 * q + 3] = v.w;
    }
    int am0 = 0, am1 = 0;
    float m0 = P[0], m1 = P[10];
#pragma unroll
    for (int cc = 1; cc < C; ++cc) {  // strict > keeps first max (jnp.argmax)
      if (P[cc] > m0) { m0 = P[cc]; am0 = cc; }
      if (P[10 + cc] > m1) { m1 = P[10 + cc]; am1 = cc; }
    }
    float u0 = 0.f, u1 = 0.f;
#pragma unroll
    for (int cc = 0; cc < C; ++cc) {
      u0 -= P[cc] * __logf(fmaxf(P[cc], 1e-10f));
      u1 -= P[10 + cc] * __logf(fmaxf(P[10 + cc], 1e-10f));
    }
    mnA = fminf(mnA, fminf(u0, u1));
    mxA = fmaxf(mxA, fmaxf(u0, u1));

    // pack acc into sign bit (unc >= 0; sign set == inaccurate), coalesced store
    unsigned s0 = __float_as_uint(u0) | ((am0 == label0) ? 0u : 0x80000000u);
    unsigned s1 = __float_as_uint(u1) | ((am1 == label0) ? 0u : 0x80000000u);
    us2[(size_t)c * 64 + lane] = make_float2(__uint_as_float(s0), __uint_as_float(s1));

#pragma unroll
    for (int q = 0; q < 5; ++q) Ycur[q] = Ynxt[q];
  }

  // per-wave reduce + spread-slot atomics (64 waves per address). No LDS scratch.
  float ce = waveSum(ceA), fo = waveSum(foA);
  float mn = waveMin(mnA), mx = waveMax(mxA);
  if (lane == 0) {
    int slot = gw & 63;
    atomicAdd(&ceSlots[slot], ce);
    atomicAdd(&focalSlots[slot], fo);
    atomicMax(&uminInvSlots[slot], ~__float_as_uint(mn));  // min via inverted bits
    atomicMax(&umaxSlots[slot], __float_as_uint(mx));
  }
}

// ---------------- pass 2: 22-bin x 4-category histogram; per-lane LDS columns,
// 4 waves share columns via ds_add_f32 (lane-indexed -> conflict/contention free).
// Block partials go to 64 spread slot-copies via global atomics (16 adds/address).
__global__ __launch_bounds__(256, 4) void pass2(
    const float4* __restrict__ us4, int n4,
    const unsigned* __restrict__ uminInvSlots, const unsigned* __restrict__ umaxSlots,
    float* __restrict__ ghist) {
  __shared__ float hist[88 * 64];  // [row][lane], 22528 B
  __shared__ float smm[2];
  const int tid = threadIdx.x, lane = tid & 63;
  for (int i = tid; i < 88 * 64; i += 256) hist[i] = 0.f;
  if (tid < 64) {
    unsigned mnInv = waveMaxU(uminInvSlots[tid]);
    unsigned mxb = waveMaxU(umaxSlots[tid]);
    if (tid == 0) { smm[0] = __uint_as_float(~mnInv); smm[1] = __uint_as_float(mxb); }
  }
  __syncthreads();
  const float umin = smm[0], delta = smm[1] - smm[0];
  float th[21];
#pragma unroll
  for (int k = 0; k < 21; ++k) th[k] = fmaf(0.05f * (float)k, delta, umin);

  const int stride = gridDim.x * 256;
  for (int i = blockIdx.x * 256 + tid; i < n4; i += stride) {
    float4 v = us4[i];
    float vv[4] = {v.x, v.y, v.z, v.w};
#pragma unroll
    for (int q = 0; q < 4; ++q) {
      unsigned b = __float_as_uint(vv[q]);
      int rb = (b >> 31) ? 44 : 0;  // acc rows 0..43, inacc rows 44..87
      float u = __uint_as_float(b & 0x7fffffffu);
      // soft_T: log(num/den) = log(num)-log(den); clamp matches frac clamp
      float e = u * 0.4342944819f;  // u / ln(10)
      float lnum = __logf(e * 0.9f);
      float lden = __logf(fmaxf((1.f - e) * 0.1f, 1e-10f));
      float x = fmaxf(lnum - lden, -23.0258509f) * 100.f;
      float s = __builtin_amdgcn_rcpf(1.f + __expf(-x));                   // sigmoid
      float t = 1.f - 2.f * __builtin_amdgcn_rcpf(__expf(2.f * u) + 1.f);  // tanh
      float wc = (1.f - s) * (1.f - t), wu = s * t;
      int j = 0;  // j = #{k: u > th_k}; le[k] <=> k >= j
#pragma unroll
      for (int k = 0; k < 21; ++k) j += (u > th[k]) ? 1 : 0;
      atomicAdd(&hist[(rb + j) * 64 + lane], wc);        // ds_add_f32
      atomicAdd(&hist[(rb + 22 + j) * 64 + lane], wu);
    }
  }
  __syncthreads();
  // tree-reduce 64 columns per row
#pragma unroll
  for (int st = 32; st >= 1; st >>= 1) {
    for (int idx = tid; idx < 88 * st; idx += 256) {
      int r = idx / st, c = idx - r * st;
      hist[r * 64 + c] += hist[r * 64 + c + st];
    }
    __syncthreads();
  }
  int slot = blockIdx.x & 63;
  for (int r = tid; r < 88; r += 256)
    atomicAdd(&ghist[slot * 88 + r], hist[r * 64]);
}

// ---------------- pass 3: reduce 64 slot-copies + scalar slots, emit outputs
__global__ __launch_bounds__(256) void pass3(
    const float* __restrict__ ghist,
    const float* __restrict__ ceSlots, const float* __restrict__ focalSlots,
    float* __restrict__ out, float invN) {
  __shared__ float hr[88];
  __shared__ float scf[2];
  int tid = threadIdx.x;
  if (tid < 88) {
    float s = 0.f;
    for (int q = 0; q < 64; ++q) s += ghist[q * 88 + tid];  // coalesced across tid
    hr[tid] = s;
  }
  if (tid >= 128 && tid < 192) {
    int l = tid - 128;
    float ce = waveSum(ceSlots[l]);
    float fo = waveSum(focalSlots[l]);
    if (l == 0) { scf[0] = ce; scf[1] = fo; }
  }
  __syncthreads();
  if (tid == 0) {
    float H0[22], H1[22], H2[22], H3[22];
    float totAU = 0.f, totIU = 0.f;
    for (int j = 0; j < 22; ++j) {
      H0[j] = hr[j]; H1[j] = hr[22 + j]; H2[j] = hr[44 + j]; H3[j] = hr[66 + j];
      totAU += H1[j]; totIU += H3[j];
    }
    float n_ac = 0.f, n_ic = 0.f, n_au = totAU, n_iu = totIU;
    float auc = 0.f, prev = 0.f;
    for (int k = 0; k < 21; ++k) {
      n_ac += H0[k]; n_ic += H2[k];
      n_au -= H1[k]; n_iu -= H3[k];
      float avu = (n_ac + n_iu) / (n_ac + n_au + n_ic + n_iu + 1e-10f);
      if (k > 0) auc += (avu + prev) * 0.5f * 0.05f;
      prev = avu;
    }
    out[0] = -logf(fmaxf(auc, 1e-10f)) + scf[1] * invN;
    out[1] = scf[0] * invN;
  }
}

extern "C" void kernel_launch(void* const* d_in, const int* in_sizes, int n_in,
                              void* d_out, int out_size, void* d_ws, size_t ws_size,
                              hipStream_t stream) {
  const float* probs = (const float*)d_in[0];
  const float* y = (const float*)d_in[1];
  float* out = (float*)d_out;
  const int N = in_sizes[0] / C;

  // ws layout (floats): [0,64) uminInv slots, [64,128) umax slots,
  // [128,192) ce slots, [192,256) focal slots, [256,5888) ghist[64][88],
  // [5888, 5888+N) us  (5888*4 = 23552 B, 16B-aligned)
  float* wsf = (float*)d_ws;
  unsigned* uminInvSlots = (unsigned*)wsf;
  unsigned* umaxSlots = (unsigned*)(wsf + 64);
  float* ceSlots = wsf + 128;
  float* focalSlots = wsf + 192;
  float* ghist = wsf + 256;
  float* us = wsf + 5888;

  hipMemsetAsync(d_ws, 0, 5888 * sizeof(float), stream);  // all accumulators -> 0

  const int nchunks = N / CHUNK_ROWS;  // 4194304 / 128 = 32768 -> 8 chunks/wave
  pass1<<<1024, 256, 0, stream>>>(probs, y, (float2*)us, uminInvSlots, umaxSlots,
                                  ceSlots, focalSlots, nchunks);
  pass2<<<1024, 256, 0, stream>>>((const float4*)us, N / 4, uminInvSlots, umaxSlots,
                                  ghist);
  pass3<<<1, 256, 0, stream>>>(ghist, ceSlots, focalSlots, out, 1.0f / (float)N);
}

// Round 6
// 385.685 us; speedup vs baseline: 1.0536x; 1.0368x over previous
//
#include <hip/hip_runtime.h>

#define C 10
#define CHUNK_ROWS 128
#define CHUNK_FLOATS 1280   // 128 rows * 10
#define CHUNK_F4 320        // float4s per chunk

__device__ __forceinline__ float waveSum(float v) {
#pragma unroll
  for (int o = 32; o > 0; o >>= 1) v += __shfl_down(v, o, 64);
  return v;
}
__device__ __forceinline__ float waveMin(float v) {
#pragma unroll
  for (int o = 32; o > 0; o >>= 1) v = fminf(v, __shfl_down(v, o, 64));
  return v;
}
__device__ __forceinline__ float waveMax(float v) {
#pragma unroll
  for (int o = 32; o > 0; o >>= 1) v = fmaxf(v, __shfl_down(v, o, 64));
  return v;
}
__device__ __forceinline__ unsigned waveMaxU(unsigned v) {
#pragma unroll
  for (int o = 32; o > 0; o >>= 1) {
    unsigned w = (unsigned)__shfl_down((int)v, o, 64);
    v = v > w ? v : w;
  }
  return v;
}

// ---------------- pass 1: register-pipelined streaming + wave-private LDS
// transpose. Coalesced float4 loads into NAMED registers (per-reg scoreboard ->
// compiler waits only the exact regs; prefetch of chunk t+1 stays in flight
// through chunk t's row phase). log() computed ONCE per element in coalesced
// layout; p and p*log(p) transposed through a wave-exclusive LDS slice with NO
// barriers (wave-synchronous, lgkmcnt only). 2-wave blocks, 20480 B LDS ->
// 8 blocks/CU, 16 waves/CU, grid 2048 = one generation, 8 chunks/wave.
__global__ __launch_bounds__(128, 4) void pass1(
    const float4* __restrict__ probs4, const float4* __restrict__ y4,
    float2* __restrict__ us2,
    unsigned* __restrict__ uminInvSlots, unsigned* __restrict__ umaxSlots,
    float* __restrict__ ceSlots, float* __restrict__ focalSlots,
    int nchunks) {
  __shared__ float lds[2 * 2 * CHUNK_FLOATS];  // [wave][p|plp][1280] = 20480 B
  const int widx = threadIdx.x >> 6, lane = threadIdx.x & 63;
  float4* const bufP = (float4*)(lds + widx * (2 * CHUNK_FLOATS));
  float4* const bufS = bufP + CHUNK_F4;  // p*log(p)

  const int gw = blockIdx.x * 2 + widx;  // global wave id, 0..4095
  const int NW = gridDim.x * 2;

  // label0 = argmax of flattened y == label of sample 0 (first max). Cache-hit.
  int label0 = 0;
  {
    const float* yf = (const float*)y4;
    float m = yf[0];
#pragma unroll
    for (int c = 1; c < C; ++c) {
      float v = yf[c];
      if (v > m) { m = v; label0 = c; }
    }
  }

  float4 P[5], Y[5];
  auto issue = [&](int c) {
    const float4* gp = probs4 + (size_t)c * CHUNK_F4 + lane;
    const float4* gy = y4 + (size_t)c * CHUNK_F4 + lane;
#pragma unroll
    for (int q = 0; q < 5; ++q) { P[q] = gp[q * 64]; Y[q] = gy[q * 64]; }
  };

  float ceA = 0.f, foA = 0.f;
  float mnA = __uint_as_float(0x7f800000u), mxA = 0.f;

  if (gw < nchunks) issue(gw);
  for (int c = gw; c < nchunks; c += NW) {
    // ---- elementwise phase (coalesced): one log per element, ce/focal with y,
    // stage p and p*lp into this wave's LDS slice.
#pragma unroll
    for (int q = 0; q < 5; ++q) {
      float4 pv = P[q], yv = Y[q];
      float lpx = __logf(fmaxf(pv.x, 1e-10f));
      float lpy = __logf(fmaxf(pv.y, 1e-10f));
      float lpz = __logf(fmaxf(pv.z, 1e-10f));
      float lpw = __logf(fmaxf(pv.w, 1e-10f));
      float4 sv = make_float4(pv.x * lpx, pv.y * lpy, pv.z * lpz, pv.w * lpw);
      // lp8 = log(max(p,1e-8)) == max(lp, log(1e-8))
      float tx = yv.x * fmaxf(lpx, -18.420681f);
      float ty = yv.y * fmaxf(lpy, -18.420681f);
      float tz = yv.z * fmaxf(lpz, -18.420681f);
      float tw = yv.w * fmaxf(lpw, -18.420681f);
      ceA -= tx + ty + tz + tw;
      foA -= tx * (1.f - pv.x) + ty * (1.f - pv.y) + tz * (1.f - pv.z) +
             tw * (1.f - pv.w);
      bufP[q * 64 + lane] = pv;
      bufS[q * 64 + lane] = sv;
    }

    // ---- prefetch next chunk into the now-dead P/Y registers; these loads
    // stay in flight through the row phase below (register-tracked waits).
    if (c + NW < nchunks) issue(c + NW);

    // ---- row phase: lane owns rows 2*lane, 2*lane+1 (80 B = 5 float4 each)
    float R[20], S[20];
#pragma unroll
    for (int q = 0; q < 5; ++q) {
      float4 v = bufP[lane * 5 + q];
      R[4 * q] = v.x; R[4 * q + 1] = v.y; R[4 * q + 2] = v.z; R[4 * q + 3] = v.w;
      float4 w = bufS[lane * 5 + q];
      S[4 * q] = w.x; S[4 * q + 1] = w.y; S[4 * q + 2] = w.z; S[4 * q + 3] = w.w;
    }
    int am0 = 0, am1 = 0;
    float m0 = R[0], m1 = R[10];
#pragma unroll
    for (int cc = 1; cc < C; ++cc) {  // strict > keeps first max (jnp.argmax)
      if (R[cc] > m0) { m0 = R[cc]; am0 = cc; }
      if (R[10 + cc] > m1) { m1 = R[10 + cc]; am1 = cc; }
    }
    float u0 = -(((S[0] + S[1]) + (S[2] + S[3])) + ((S[4] + S[5]) + (S[6] + S[7])) +
                 (S[8] + S[9]));
    float u1 = -(((S[10] + S[11]) + (S[12] + S[13])) +
                 ((S[14] + S[15]) + (S[16] + S[17])) + (S[18] + S[19]));
    mnA = fminf(mnA, fminf(u0, u1));
    mxA = fmaxf(mxA, fmaxf(u0, u1));

    // pack acc into sign bit (unc >= 0; sign set == inaccurate), coalesced store
    unsigned s0 = __float_as_uint(u0) | ((am0 == label0) ? 0u : 0x80000000u);
    unsigned s1 = __float_as_uint(u1) | ((am1 == label0) ? 0u : 0x80000000u);
    us2[(size_t)c * 64 + lane] = make_float2(__uint_as_float(s0), __uint_as_float(s1));
  }

  // per-wave reduce + spread-slot atomics (64 waves per address). No LDS scratch.
  float ce = waveSum(ceA), fo = waveSum(foA);
  float mn = waveMin(mnA), mx = waveMax(mxA);
  if (lane == 0) {
    int slot = gw & 63;
    atomicAdd(&ceSlots[slot], ce);
    atomicAdd(&focalSlots[slot], fo);
    atomicMax(&uminInvSlots[slot], ~__float_as_uint(mn));  // min via inverted bits
    atomicMax(&umaxSlots[slot], __float_as_uint(mx));
  }
}

// ---------------- pass 2: 22-bin x 4-category histogram; per-lane LDS columns,
// 4 waves share columns via ds_add_f32 (lane-indexed -> conflict/contention free).
// Block partials go to 64 spread slot-copies via global atomics (16 adds/address).
__global__ __launch_bounds__(256, 4) void pass2(
    const float4* __restrict__ us4, int n4,
    const unsigned* __restrict__ uminInvSlots, const unsigned* __restrict__ umaxSlots,
    float* __restrict__ ghist) {
  __shared__ float hist[88 * 64];  // [row][lane], 22528 B
  __shared__ float smm[2];
  const int tid = threadIdx.x, lane = tid & 63;
  for (int i = tid; i < 88 * 64; i += 256) hist[i] = 0.f;
  if (tid < 64) {
    unsigned mnInv = waveMaxU(uminInvSlots[tid]);
    unsigned mxb = waveMaxU(umaxSlots[tid]);
    if (tid == 0) { smm[0] = __uint_as_float(~mnInv); smm[1] = __uint_as_float(mxb); }
  }
  __syncthreads();
  const float umin = smm[0], delta = smm[1] - smm[0];
  float th[21];
#pragma unroll
  for (int k = 0; k < 21; ++k) th[k] = fmaf(0.05f * (float)k, delta, umin);

  const int stride = gridDim.x * 256;
  for (int i = blockIdx.x * 256 + tid; i < n4; i += stride) {
    float4 v = us4[i];
    float vv[4] = {v.x, v.y, v.z, v.w};
#pragma unroll
    for (int q = 0; q < 4; ++q) {
      unsigned b = __float_as_uint(vv[q]);
      int rb = (b >> 31) ? 44 : 0;  // acc rows 0..43, inacc rows 44..87
      float u = __uint_as_float(b & 0x7fffffffu);
      // soft_T: log(num/den) = log(num)-log(den); clamp matches frac clamp
      float e = u * 0.4342944819f;  // u / ln(10)
      float lnum = __logf(e * 0.9f);
      float lden = __logf(fmaxf((1.f - e) * 0.1f, 1e-10f));
      float x = fmaxf(lnum - lden, -23.0258509f) * 100.f;
      float s = __builtin_amdgcn_rcpf(1.f + __expf(-x));                   // sigmoid
      float t = 1.f - 2.f * __builtin_amdgcn_rcpf(__expf(2.f * u) + 1.f);  // tanh
      float wc = (1.f - s) * (1.f - t), wu = s * t;
      int j = 0;  // j = #{k: u > th_k}; le[k] <=> k >= j
#pragma unroll
      for (int k = 0; k < 21; ++k) j += (u > th[k]) ? 1 : 0;
      atomicAdd(&hist[(rb + j) * 64 + lane], wc);        // ds_add_f32
      atomicAdd(&hist[(rb + 22 + j) * 64 + lane], wu);
    }
  }
  __syncthreads();
  // tree-reduce 64 columns per row
#pragma unroll
  for (int st = 32; st >= 1; st >>= 1) {
    for (int idx = tid; idx < 88 * st; idx += 256) {
      int r = idx / st, c = idx - r * st;
      hist[r * 64 + c] += hist[r * 64 + c + st];
    }
    __syncthreads();
  }
  int slot = blockIdx.x & 63;
  for (int r = tid; r < 88; r += 256)
    atomicAdd(&ghist[slot * 88 + r], hist[r * 64]);
}

// ---------------- pass 3: reduce 64 slot-copies + scalar slots, emit outputs
__global__ __launch_bounds__(256) void pass3(
    const float* __restrict__ ghist,
    const float* __restrict__ ceSlots, const float* __restrict__ focalSlots,
    float* __restrict__ out, float invN) {
  __shared__ float hr[88];
  __shared__ float scf[2];
  int tid = threadIdx.x;
  if (tid < 88) {
    float s = 0.f;
    for (int q = 0; q < 64; ++q) s += ghist[q * 88 + tid];  // coalesced across tid
    hr[tid] = s;
  }
  if (tid >= 128 && tid < 192) {
    int l = tid - 128;
    float ce = waveSum(ceSlots[l]);
    float fo = waveSum(focalSlots[l]);
    if (l == 0) { scf[0] = ce; scf[1] = fo; }
  }
  __syncthreads();
  if (tid == 0) {
    float H0[22], H1[22], H2[22], H3[22];
    float totAU = 0.f, totIU = 0.f;
    for (int j = 0; j < 22; ++j) {
      H0[j] = hr[j]; H1[j] = hr[22 + j]; H2[j] = hr[44 + j]; H3[j] = hr[66 + j];
      totAU += H1[j]; totIU += H3[j];
    }
    float n_ac = 0.f, n_ic = 0.f, n_au = totAU, n_iu = totIU;
    float auc = 0.f, prev = 0.f;
    for (int k = 0; k < 21; ++k) {
      n_ac += H0[k]; n_ic += H2[k];
      n_au -= H1[k]; n_iu -= H3[k];
      float avu = (n_ac + n_iu) / (n_ac + n_au + n_ic + n_iu + 1e-10f);
      if (k > 0) auc += (avu + prev) * 0.5f * 0.05f;
      prev = avu;
    }
    out[0] = -logf(fmaxf(auc, 1e-10f)) + scf[1] * invN;
    out[1] = scf[0] * invN;
  }
}

extern "C" void kernel_launch(void* const* d_in, const int* in_sizes, int n_in,
                              void* d_out, int out_size, void* d_ws, size_t ws_size,
                              hipStream_t stream) {
  const float* probs = (const float*)d_in[0];
  const float* y = (const float*)d_in[1];
  float* out = (float*)d_out;
  const int N = in_sizes[0] / C;

  // ws layout (floats): [0,64) uminInv slots, [64,128) umax slots,
  // [128,192) ce slots, [192,256) focal slots, [256,5888) ghist[64][88],
  // [5888, 5888+N) us  (5888*4 = 23552 B, 16B-aligned)
  float* wsf = (float*)d_ws;
  unsigned* uminInvSlots = (unsigned*)wsf;
  unsigned* umaxSlots = (unsigned*)(wsf + 64);
  float* ceSlots = wsf + 128;
  float* focalSlots = wsf + 192;
  float* ghist = wsf + 256;
  float* us = wsf + 5888;

  hipMemsetAsync(d_ws, 0, 5888 * sizeof(float), stream);  // all accumulators -> 0

  const int nchunks = N / CHUNK_ROWS;  // 4194304/128 = 32768 -> 8 chunks/wave
  pass1<<<2048, 128, 0, stream>>>((const float4*)probs, (const float4*)y,
                                  (float2*)us, uminInvSlots, umaxSlots,
                                  ceSlots, focalSlots, nchunks);
  pass2<<<1024, 256, 0, stream>>>((const float4*)us, N / 4, uminInvSlots, umaxSlots,
                                  ghist);
  pass3<<<1, 256, 0, stream>>>(ghist, ceSlots, focalSlots, out, 1.0f / (float)N);
}